// Round 1
// 454.432 us; speedup vs baseline: 1.0158x; 1.0158x over previous
//
#include <hip/hip_runtime.h>

// Depthwise conv1d, B=8 L=16384 C=512 K=31, SAME padding, fp32.
// out[b,l,c] = sum_k x[b, l+k-15, c] * w[k,c] + bias[c]
//
// R2: the TL=16 triangle kernel (461 us) is latency-bound: ~115 live VGPRs,
// 4 waves/SIMD, and load->use distance ~0 means each wave stalls on vmcnt
// ~46x with few loads in flight (effective BW ~2.3 TB/s, VALUBusy ~7%).
// Restructure as a register sliding window so register demand is CONSTANT in
// tile length:
//   - xw[32] circular window (31 live rows + 1 free slot), wk[31], tmp[4]
//     prefetch queue  -> ~150 VGPR regardless of TL.
//   - TL=64: halo re-read factor (TL+30+4)/TL = 1.53x vs 2.875x at TL=16.
//   - A row is loaded 5 steps (~62 FMAs each) before first use: ~650 cycles
//     of structural latency cover per wave, on top of 3 waves/SIMD TLP.
//   - All window indices are (j + const) & 31 inside a 32-step fully-unrolled
//     body with the outer loop stepping base += 32 (#pragma unroll 1), so
//     every index is compile-time constant -> registers, not scratch.
//   - XCD swizzle: dispatch d -> tile (d&7)*256 + (d>>3): each XCD owns a
//     contiguous L range, so the 30-row halo shared by adjacent tiles is a
//     same-XCD L2 hit instead of an L3/HBM refetch.

#define BB 8
#define LL 16384
#define CC 512
#define KK 31
#define PAD 15
#define TL 64
#define TILES_PER_B (LL / TL)      // 256
#define NWG (BB * TILES_PER_B)     // 2048
#define PD 4                       // prefetch queue depth (rows)
#define WIN 32                     // window slots, power of 2 > KK

__global__ __launch_bounds__(256)
void depthconv1d_2680059592713_kernel(const float* __restrict__ x,
                                      const float* __restrict__ w,
                                      const float* __restrict__ bias,
                                      float* __restrict__ out) {
    const int c2 = threadIdx.x;                   // 0..255 -> float2 channel group
    const int d  = blockIdx.x;
    // XCD-aware swizzle (NWG % 8 == 0 so this is bijective): dispatch d goes to
    // XCD d%8; remap so XCD k gets logical tiles [k*256, (k+1)*256) contiguously.
    const int tile = (d & 7) * (NWG / 8) + (d >> 3);
    const int b    = tile >> 8;                   // / TILES_PER_B
    const int l0   = (tile & (TILES_PER_B - 1)) * TL;
    const int c    = c2 * 2;

    const float* xb = x + ((size_t)b * LL) * CC + c;

    // Bounds-checked row load; l0 + r is block-uniform -> scalar branch.
    auto loadrow = [&](int r) -> float2 {
        const int lr = l0 + r;
        if (lr >= 0 && lr < LL) {
            return *(const float2*)(xb + (size_t)lr * CC);
        }
        return make_float2(0.f, 0.f);
    };

    // Prologue: fill window with rows -15..15 (row r lives in slot r & 31),
    // and the prefetch queue with rows 16..19. Issue these before the weight
    // loads so the long-latency x reads start first.
    float2 xw[WIN];
#pragma unroll
    for (int r = -PAD; r <= PAD; ++r) {
        xw[r & (WIN - 1)] = loadrow(r);
    }

    float2 tmp[PD];
#pragma unroll
    for (int p = 0; p < PD; ++p) {
        tmp[p] = loadrow(PAD + 1 + p);            // rows 16..19
    }

    // Weights: w is (K, C, 1) flat k*C + c. 31 x float2 = 62 VGPRs. These hit
    // L2 (62 KB shared by all blocks).
    float2 wk[KK];
#pragma unroll
    for (int k = 0; k < KK; ++k) {
        wk[k] = *(const float2*)(w + k * CC + c);
    }
    const float2 bv = *(const float2*)(bias + c);

    float* ob = out + (((size_t)b * LL) + l0) * CC + c;

    // Steady state: at step t = base + j,
    //   1. install row t+16 (loaded PD steps ago) into its window slot,
    //   2. refill the queue slot with row t+20,
    //   3. 31-tap FMA for output row t, 4. store.
    // Slot indices depend only on j because base % WIN == 0.
#pragma unroll 1
    for (int base = 0; base < TL; base += WIN) {
#pragma unroll
        for (int j = 0; j < WIN; ++j) {
            xw[(j + PAD + 1) & (WIN - 1)] = tmp[j & (PD - 1)];
            tmp[j & (PD - 1)] = loadrow(base + j + PAD + 1 + PD);

            float2 acc = bv;
#pragma unroll
            for (int k = 0; k < KK; ++k) {
                const float2 xv = xw[(j + k - PAD) & (WIN - 1)];
                acc.x = fmaf(xv.x, wk[k].x, acc.x);
                acc.y = fmaf(xv.y, wk[k].y, acc.y);
            }

            *(float2*)(ob + (size_t)(base + j) * CC) = acc;
        }
    }
}

extern "C" void kernel_launch(void* const* d_in, const int* in_sizes, int n_in,
                              void* d_out, int out_size, void* d_ws, size_t ws_size,
                              hipStream_t stream) {
    const float* x    = (const float*)d_in[0];
    const float* w    = (const float*)d_in[1];
    const float* bias = (const float*)d_in[2];
    float* out        = (float*)d_out;

    hipLaunchKernelGGL(depthconv1d_2680059592713_kernel,
                       dim3(NWG), dim3(256), 0, stream,
                       x, w, bias, out);
}